// Round 9
// baseline (60.623 us; speedup 1.0000x reference)
//
#include <hip/hip_runtime.h>
#include <cmath>

#define NB   8
#define NTT  1024
#define MM   64
#define LL   16
#define EE   128
#define NTB  8          // (b,nt) positions per block == waves per block

typedef float f32x4 __attribute__((ext_vector_type(4)));
typedef float f32x2 __attribute__((ext_vector_type(2)));

__global__ __launch_bounds__(512, 8) void a2l_kernel(
    const float* __restrict__ agent,
    const float* __restrict__ lane,
    const float* __restrict__ W,
    const float* __restrict__ bias,
    float* __restrict__ out)
{
    __shared__ f32x4 sE0[NTB][MM];   // argmin point
    __shared__ f32x4 sE1[NTB][MM];   // l = 0 slice
    __shared__ f32x4 sE2[NTB][MM];   // l = 15 slice

    const int tid       = threadIdx.x;
    const int wv        = tid >> 6;          // wave id == nt, 0..7
    const int ln        = tid & 63;          // lane
    const int bidx_base = blockIdx.x * NTB;  // 8-aligned => same b for all 8
    const int b         = bidx_base >> 10;
    const int bidx      = bidx_base + wv;

    // ---- weight/bias register loads (2 consecutive channels per thread) ----
    const int ch = ln * 2;                   // 0..126, full-wave channel span
    float w[2][12];
#pragma unroll
    for (int j = 0; j < 2; ++j) {
        const f32x4* wp = reinterpret_cast<const f32x4*>(W + (size_t)(ch + j) * 12);
        const f32x4 w0 = wp[0], w1 = wp[1], w2 = wp[2];
        w[j][0] = w0.x; w[j][1]  = w0.y; w[j][2]  = w0.z; w[j][3]  = w0.w;
        w[j][4] = w1.x; w[j][5]  = w1.y; w[j][6]  = w1.z; w[j][7]  = w1.w;
        w[j][8] = w2.x; w[j][9]  = w2.y; w[j][10] = w2.z; w[j][11] = w2.w;
    }
    const float bb0 = bias[ch + 0];
    const float bb1 = bias[ch + 1];

    // ---- Phase 1: each lane computes the edge for (bidx, m = lane) ----
    {
        const int m = ln;
        const f32x4* ap = reinterpret_cast<const f32x4*>(agent + (size_t)bidx * 8);
        const f32x4 a0 = ap[0];
        const f32x4 a1 = ap[1];
        const float px = a0.x, py = a0.y, ps = a0.w, pc = a1.x;
        const bool z1 = (a0.x == 0.f) & (a0.y == 0.f) & (a0.z == 0.f) & (a0.w == 0.f) &
                        (a1.x == 0.f) & (a1.y == 0.f) & (a1.z == 0.f) & (a1.w == 0.f);
        const float f1 = z1 ? 0.f : 1.f;

        const f32x4* lp = reinterpret_cast<const f32x4*>(lane + ((size_t)b * MM + m) * 64);

        float best = INFINITY;
        f32x4 eMin = (f32x4)(0.f);
        f32x4 eL0  = (f32x4)(0.f);
        f32x4 eL15 = (f32x4)(0.f);
#pragma unroll
        for (int l = 0; l < LL; ++l) {
            const f32x4 lv = lp[l];                   // lx, ly, ls, lc
            const bool z2 = (lv.x == 0.f) & (lv.y == 0.f) & (lv.z == 0.f) & (lv.w == 0.f);
            const float f = z2 ? 0.f : f1;
            const float dxw = px - lv.x;
            const float dyw = py - lv.y;
            f32x4 v;
            v.x = (dxw * lv.w + dyw * lv.z) * 0.1f * f;   // delta_x / 10
            v.y = (dyw * lv.w - dxw * lv.z) * 0.1f * f;   // delta_y / 10
            v.z = (ps * lv.w - pc * lv.z) * f;            // ds
            v.w = (pc * lv.w + ps * lv.z) * f;            // dc
            const float ad = fabsf(v.x);
            if (ad < best) { best = ad; eMin = v; }       // strict < keeps FIRST min
            if (l == 0)      eL0  = v;
            if (l == LL - 1) eL15 = v;
        }
        sE0[wv][m] = eMin;
        sE1[wv][m] = eL0;
        sE2[wv][m] = eL15;
    }
    // NO __syncthreads(): wave wv wrote sE*[wv][*] and is the only reader of it.

    // ---- Phase 2: wave streams its 32KB region; one row m per iteration ----
    // m is wave-uniform -> LDS reads broadcast; 64 lanes x 8B = 512B contiguous
    // per store instruction, advancing linearly.
    float* outp = out + (size_t)bidx * (MM * EE);

#pragma unroll 8
    for (int m = 0; m < MM; ++m) {
        const f32x4 p = sE0[wv][m];
        const f32x4 q = sE1[wv][m];
        const f32x4 r = sE2[wv][m];
        f32x2 res;
        res.x = bb0 + p.x*w[0][0] + p.y*w[0][1] + p.z*w[0][2]  + p.w*w[0][3]
                    + q.x*w[0][4] + q.y*w[0][5] + q.z*w[0][6]  + q.w*w[0][7]
                    + r.x*w[0][8] + r.y*w[0][9] + r.z*w[0][10] + r.w*w[0][11];
        res.y = bb1 + p.x*w[1][0] + p.y*w[1][1] + p.z*w[1][2]  + p.w*w[1][3]
                    + q.x*w[1][4] + q.y*w[1][5] + q.z*w[1][6]  + q.w*w[1][7]
                    + r.x*w[1][8] + r.y*w[1][9] + r.z*w[1][10] + r.w*w[1][11];
        *reinterpret_cast<f32x2*>(outp + (size_t)m * EE + ch) = res;
    }
}

extern "C" void kernel_launch(void* const* d_in, const int* in_sizes, int n_in,
                              void* d_out, int out_size, void* d_ws, size_t ws_size,
                              hipStream_t stream) {
    const float* agent = (const float*)d_in[0];
    const float* lane  = (const float*)d_in[1];
    const float* W     = (const float*)d_in[2];
    const float* bias  = (const float*)d_in[3];
    float* out = (float*)d_out;

    dim3 grid((NB * NTT) / NTB);   // 1024 blocks
    dim3 block(512);
    a2l_kernel<<<grid, block, 0, stream>>>(agent, lane, W, bias, out);
}

// Round 10
// 56.613 us; speedup vs baseline: 1.0708x; 1.0708x over previous
//
#include <hip/hip_runtime.h>
#include <cmath>

#define NB   8
#define NTT  1024
#define MM   64
#define LL   16
#define EE   128
#define NTB  8          // (b,nt) positions per block == waves per block

typedef float f32x4 __attribute__((ext_vector_type(4)));

__global__ __launch_bounds__(512, 6) void a2l_kernel(
    const float* __restrict__ agent,
    const float* __restrict__ lane,
    const float* __restrict__ W,
    const float* __restrict__ bias,
    float* __restrict__ out)
{
    __shared__ f32x4 sE0[NTB][MM];   // argmin point
    __shared__ f32x4 sE1[NTB][MM];   // l = 0 slice
    __shared__ f32x4 sE2[NTB][MM];   // l = 15 slice

    const int tid       = threadIdx.x;
    const int wv        = tid >> 6;          // wave id == nt, 0..7
    const int ln        = tid & 63;          // lane
    const int bidx_base = blockIdx.x * NTB;  // 8-aligned => same b for all 8
    const int b         = bidx_base >> 10;
    const int bidx      = bidx_base + wv;

    // ---- weight/bias register loads (4 consecutive channels per thread) ----
    const int ch = (ln & 31) * 4;            // 0..124
    float w[4][12];
#pragma unroll
    for (int j = 0; j < 4; ++j) {
        const f32x4* wp = reinterpret_cast<const f32x4*>(W + (size_t)(ch + j) * 12);
        const f32x4 w0 = wp[0], w1 = wp[1], w2 = wp[2];
        w[j][0] = w0.x; w[j][1]  = w0.y; w[j][2]  = w0.z; w[j][3]  = w0.w;
        w[j][4] = w1.x; w[j][5]  = w1.y; w[j][6]  = w1.z; w[j][7]  = w1.w;
        w[j][8] = w2.x; w[j][9]  = w2.y; w[j][10] = w2.z; w[j][11] = w2.w;
    }
    const f32x4 bb = *reinterpret_cast<const f32x4*>(bias + ch);

    // ---- Phase 1: each lane computes the edge for (bidx, m = lane) ----
    {
        const int m = ln;
        const f32x4* ap = reinterpret_cast<const f32x4*>(agent + (size_t)bidx * 8);
        const f32x4 a0 = ap[0];
        const f32x4 a1 = ap[1];
        const float px = a0.x, py = a0.y, ps = a0.w, pc = a1.x;
        const bool z1 = (a0.x == 0.f) & (a0.y == 0.f) & (a0.z == 0.f) & (a0.w == 0.f) &
                        (a1.x == 0.f) & (a1.y == 0.f) & (a1.z == 0.f) & (a1.w == 0.f);
        const float f1 = z1 ? 0.f : 1.f;

        const f32x4* lp = reinterpret_cast<const f32x4*>(lane + ((size_t)b * MM + m) * 64);

        float best = INFINITY;
        f32x4 eMin = (f32x4)(0.f);
        f32x4 eL0  = (f32x4)(0.f);
        f32x4 eL15 = (f32x4)(0.f);
#pragma unroll
        for (int l = 0; l < LL; ++l) {
            const f32x4 lv = lp[l];                   // lx, ly, ls, lc
            const bool z2 = (lv.x == 0.f) & (lv.y == 0.f) & (lv.z == 0.f) & (lv.w == 0.f);
            const float f = z2 ? 0.f : f1;
            const float dxw = px - lv.x;
            const float dyw = py - lv.y;
            f32x4 v;
            v.x = (dxw * lv.w + dyw * lv.z) * 0.1f * f;   // delta_x / 10
            v.y = (dyw * lv.w - dxw * lv.z) * 0.1f * f;   // delta_y / 10
            v.z = (ps * lv.w - pc * lv.z) * f;            // ds
            v.w = (pc * lv.w + ps * lv.z) * f;            // dc
            const float ad = fabsf(v.x);
            if (ad < best) { best = ad; eMin = v; }       // strict < keeps FIRST min
            if (l == 0)      eL0  = v;
            if (l == LL - 1) eL15 = v;
        }
        sE0[wv][m] = eMin;
        sE1[wv][m] = eL0;
        sE2[wv][m] = eL15;
    }
    // NO __syncthreads(): wave wv wrote sE*[wv][*] and is the only reader of it.

    // ---- Phase 2: wave wv streams its contiguous 32KB region linearly ----
    const int mh = ln >> 5;                  // 0 or 1
    float* outp = out + (size_t)bidx * (MM * EE);

#pragma unroll 4
    for (int it = 0; it < 32; ++it) {
        const int m = it * 2 + mh;
        const f32x4 p = sE0[wv][m];
        const f32x4 q = sE1[wv][m];
        const f32x4 r = sE2[wv][m];
        f32x4 res;
        res.x = bb.x + p.x*w[0][0] + p.y*w[0][1] + p.z*w[0][2]  + p.w*w[0][3]
                     + q.x*w[0][4] + q.y*w[0][5] + q.z*w[0][6]  + q.w*w[0][7]
                     + r.x*w[0][8] + r.y*w[0][9] + r.z*w[0][10] + r.w*w[0][11];
        res.y = bb.y + p.x*w[1][0] + p.y*w[1][1] + p.z*w[1][2]  + p.w*w[1][3]
                     + q.x*w[1][4] + q.y*w[1][5] + q.z*w[1][6]  + q.w*w[1][7]
                     + r.x*w[1][8] + r.y*w[1][9] + r.z*w[1][10] + r.w*w[1][11];
        res.z = bb.z + p.x*w[2][0] + p.y*w[2][1] + p.z*w[2][2]  + p.w*w[2][3]
                     + q.x*w[2][4] + q.y*w[2][5] + q.z*w[2][6]  + q.w*w[2][7]
                     + r.x*w[2][8] + r.y*w[2][9] + r.z*w[2][10] + r.w*w[2][11];
        res.w = bb.w + p.x*w[3][0] + p.y*w[3][1] + p.z*w[3][2]  + p.w*w[3][3]
                     + q.x*w[3][4] + q.y*w[3][5] + q.z*w[3][6]  + q.w*w[3][7]
                     + r.x*w[3][8] + r.y*w[3][9] + r.z*w[3][10] + r.w*w[3][11];
        *reinterpret_cast<f32x4*>(outp + (size_t)m * EE + ch) = res;
    }
}

extern "C" void kernel_launch(void* const* d_in, const int* in_sizes, int n_in,
                              void* d_out, int out_size, void* d_ws, size_t ws_size,
                              hipStream_t stream) {
    const float* agent = (const float*)d_in[0];
    const float* lane  = (const float*)d_in[1];
    const float* W     = (const float*)d_in[2];
    const float* bias  = (const float*)d_in[3];
    float* out = (float*)d_out;

    dim3 grid((NB * NTT) / NTB);   // 1024 blocks
    dim3 block(512);
    a2l_kernel<<<grid, block, 0, stream>>>(agent, lane, W, bias, out);
}